// Round 1
// 4535.406 us; speedup vs baseline: 1.0120x; 1.0120x over previous
//
#include <hip/hip_runtime.h>
#include <stdint.h>

// BLT_encoder: 6-layer GPT fwd, fp32 in/out, f16x2 split-precision MFMA compute.
// B=4 T=1024 C=768 H=12 L=6 V=32000. Outputs: [argmax(4096) | maxprob(4096) | logsoftmax(131072000)] fp32.
// R1: head GEMM + FF1 moved to k_hgemm — 256x128-tile 3-stage pipelined GEMM with
//     counted vmcnt (never drains mid-loop), T2 XOR LDS swizzle, XCD block swizzle, setprio.

#define B_ 4
#define T_ 1024
#define C_ 768
#define H_ 12
#define L_ 6
#define V_ 32000
#define CQ_ 2304
#define F_ 3072

typedef _Float16 f16;
typedef _Float16 f16x4 __attribute__((ext_vector_type(4)));
typedef _Float16 f16x8 __attribute__((ext_vector_type(8)));
typedef float f32x4 __attribute__((ext_vector_type(4)));

__device__ __forceinline__ f32x4 mfma16(f16x8 a, f16x8 b, f32x4 c) {
  return __builtin_amdgcn_mfma_f32_16x16x32_f16(a, b, c, 0, 0, 0);
}

__device__ __forceinline__ void gl_lds16(const void* g, void* l) {
  __builtin_amdgcn_global_load_lds((const __attribute__((address_space(1))) void*)g,
                                   (__attribute__((address_space(3))) void*)l, 16, 0, 0);
}

// ---------------- transpose + fp32 -> (f16 hi, f16 lo) split ----------------
// src: [batch][K][N] fp32 row-major.  dst hi/lo: [batch][N][K] f16.
__global__ __launch_bounds__(256) void k_tsplit(const float* __restrict__ src,
    f16* __restrict__ dh, f16* __restrict__ dl, int K, int N,
    long long sS, long long dS)
{
  __shared__ float tile[64][68];
  src += (size_t)blockIdx.z * sS;
  dh += (size_t)blockIdx.z * dS;
  dl += (size_t)blockIdx.z * dS;
  const int t = threadIdx.x, tx = t & 15, ty = t >> 4;
  const int k0 = blockIdx.y * 64, n0 = blockIdx.x * 64;
#pragma unroll
  for (int rr = 0; rr < 4; rr++) {
    int row = ty + rr * 16;
    *(float4*)(&tile[row][tx * 4]) = *(const float4*)(src + (size_t)(k0 + row) * N + n0 + tx * 4);
  }
  __syncthreads();
#pragma unroll
  for (int rr = 0; rr < 4; rr++) {
    int nr = ty + rr * 16;
    f16x4 vh, vl;
#pragma unroll
    for (int j = 0; j < 4; j++) {
      float v = tile[tx * 4 + j][nr];
      f16 hv = (f16)v;
      vh[j] = hv;
      vl[j] = (f16)(v - (float)hv);
    }
    size_t o = (size_t)(n0 + nr) * K + k0 + tx * 4;
    *(f16x4*)(dh + o) = vh;
    *(f16x4*)(dl + o) = vl;
  }
}

// ---------------- concat bq|bk|bv -> [L][2304] fp32 ----------------
__global__ __launch_bounds__(256) void k_bqkv(const float* __restrict__ bq, const float* __restrict__ bk,
    const float* __restrict__ bv, float* __restrict__ dst)
{
  int g = blockIdx.x * 256 + threadIdx.x;   // < 6*2304
  int lr = g / CQ_, j = g - lr * CQ_;
  float v;
  if (j < 768) v = bq[lr * 768 + j];
  else if (j < 1536) v = bk[lr * 768 + j - 768];
  else v = bv[lr * 768 + j - 1536];
  dst[g] = v;
}

// ---------------- embedding: x = tok_emb[idx] + pos_emb ----------------
__global__ __launch_bounds__(256) void k_embed(const int* __restrict__ idx, const float* __restrict__ tok,
    const float* __restrict__ pos, float* __restrict__ x)
{
  int g = blockIdx.x * 256 + threadIdx.x;   // 786432 threads, 4 elems each
  int e = g * 4;
  int bt = e / C_;
  int c = e - bt * C_;
  int tt = bt & (T_ - 1);
  float4 a = *(const float4*)(tok + (size_t)idx[bt] * C_ + c);
  float4 p = *(const float4*)(pos + (size_t)tt * C_ + c);
  float4 o = {a.x + p.x, a.y + p.y, a.z + p.z, a.w + p.w};
  *(float4*)(x + e) = o;
}

// ---------------- LayerNorm: fp32 x row -> split f16 pair ----------------
__global__ __launch_bounds__(256) void k_ln(const float* __restrict__ x, const float* __restrict__ gg,
    const float* __restrict__ bb, f16* __restrict__ oh, f16* __restrict__ ol)
{
  __shared__ float red0[256], red1[256];
  const int row = blockIdx.x, t = threadIdx.x;
  const float* xr = x + (size_t)row * C_;
  float v0 = xr[t], v1 = xr[t + 256], v2 = xr[t + 512];
  red0[t] = v0 + v1 + v2;
  red1[t] = v0 * v0 + v1 * v1 + v2 * v2;
  __syncthreads();
  for (int off = 128; off > 0; off >>= 1) {
    if (t < off) { red0[t] += red0[t + off]; red1[t] += red1[t + off]; }
    __syncthreads();
  }
  const float mean = red0[0] * (1.f / C_);
  const float var = red1[0] * (1.f / C_) - mean * mean;
  const float rstd = rsqrtf(var + 1e-5f);
  const size_t o = (size_t)row * C_;
  float vv[3] = {v0, v1, v2};
#pragma unroll
  for (int i = 0; i < 3; i++) {
    int c = t + i * 256;
    float hv = (vv[i] - mean) * rstd * gg[c] + bb[c];
    f16 hh = (f16)hv;
    oh[o + c] = hh;
    ol[o + c] = (f16)(hv - (float)hh);
  }
}

// ---------------- split-precision GEMM: C[M,N] = A[M,K] * B[K,N] (+epilogue) ----------------
// A given as hi/lo f16 [M][K]; B given transposed hi/lo f16 [N][K].
// EPI: 0 = bias, split-f16 out.  1 = bias + exact GELU, split-f16 out.
//      2 = bias + fp32 residual add, fp32 out.  3 = no bias, fp32 out.
template<int EPI>
__global__ __launch_bounds__(256, 2) void k_gemm(
    const f16* __restrict__ Ah, const f16* __restrict__ Al,
    const f16* __restrict__ Bh, const f16* __restrict__ Bl,
    const float* __restrict__ bias, const float* __restrict__ resid,
    float* __restrict__ outf, f16* __restrict__ outh, f16* __restrict__ outl,
    int M, int N, int K)
{
  __shared__ f16 sAh[128 * 32], sAl[128 * 32], sBh[128 * 32], sBl[128 * 32];
  const int t = threadIdx.x;
  const int l = t & 63, l15 = l & 15, quad = l >> 4;
  const int w = t >> 6;
  const int wm = (w >> 1) * 64, wn = (w & 1) * 64;
  const int m0 = blockIdx.y * 128, n0 = blockIdx.x * 128;
  const int r0 = t >> 2;            // staging row (pass 0)
  const int c8 = (t & 3) * 8;       // staging col

  f32x4 acc[4][4];
#pragma unroll
  for (int i = 0; i < 4; i++)
#pragma unroll
    for (int j = 0; j < 4; j++) acc[i][j] = (f32x4){0.f, 0.f, 0.f, 0.f};

  for (int k0 = 0; k0 < K; k0 += 32) {
    __syncthreads();
    const size_t ga0 = (size_t)(m0 + r0) * K + k0 + c8;
    const size_t ga1 = (size_t)(m0 + 64 + r0) * K + k0 + c8;
    const size_t gb0 = (size_t)(n0 + r0) * K + k0 + c8;
    const size_t gb1 = (size_t)(n0 + 64 + r0) * K + k0 + c8;
    gl_lds16(Ah + ga0, sAh + (size_t)t * 8);
    gl_lds16(Ah + ga1, sAh + (size_t)(256 + t) * 8);
    gl_lds16(Al + ga0, sAl + (size_t)t * 8);
    gl_lds16(Al + ga1, sAl + (size_t)(256 + t) * 8);
    gl_lds16(Bh + gb0, sBh + (size_t)t * 8);
    gl_lds16(Bh + gb1, sBh + (size_t)(256 + t) * 8);
    gl_lds16(Bl + gb0, sBl + (size_t)t * 8);
    gl_lds16(Bl + gb1, sBl + (size_t)(256 + t) * 8);
    __syncthreads();
    f16x8 fah[4], fal[4], fbh[4], fbl[4];
#pragma unroll
    for (int i = 0; i < 4; i++) {
      int ra = (wm + i * 16 + l15) * 32 + quad * 8;
      fah[i] = *(const f16x8*)(sAh + ra);
      fal[i] = *(const f16x8*)(sAl + ra);
    }
#pragma unroll
    for (int j = 0; j < 4; j++) {
      int rb = (wn + j * 16 + l15) * 32 + quad * 8;
      fbh[j] = *(const f16x8*)(sBh + rb);
      fbl[j] = *(const f16x8*)(sBl + rb);
    }
#pragma unroll
    for (int i = 0; i < 4; i++)
#pragma unroll
      for (int j = 0; j < 4; j++) {
        acc[i][j] = mfma16(fal[i], fbh[j], acc[i][j]);
        acc[i][j] = mfma16(fah[i], fbl[j], acc[i][j]);
        acc[i][j] = mfma16(fah[i], fbh[j], acc[i][j]);
      }
  }

#pragma unroll
  for (int j = 0; j < 4; j++) {
    int col = n0 + wn + j * 16 + l15;
    float bv = 0.f;
    if constexpr (EPI != 3) bv = bias[col];
#pragma unroll
    for (int i = 0; i < 4; i++) {
      int rowb = m0 + wm + i * 16 + quad * 4;
#pragma unroll
      for (int r = 0; r < 4; r++) {
        size_t o = (size_t)(rowb + r) * N + col;
        float v = acc[i][j][r] + bv;
        if constexpr (EPI == 1) v = 0.5f * v * (1.f + erff(v * 0.70710678118f));
        if constexpr (EPI == 0 || EPI == 1) {
          f16 hv = (f16)v;
          outh[o] = hv;
          outl[o] = (f16)(v - (float)hv);
        } else if constexpr (EPI == 2) {
          outf[o] = resid[o] + v;
        } else {
          outf[o] = v;
        }
      }
    }
  }
}

// ---------------- 256x128-tile 3-stage pipelined split-precision GEMM ----------------
// A hi/lo [M][K] f16, B hi/lo [N][K] f16 (transposed). BK=32, 512 threads = 8 waves
// (4M x 2N, 64x64 output each). 3 LDS stages (144 KiB) -> counted vmcnt keeps 9 loads
// in flight across the per-tile wait (T3+T4). T2 XOR swizzle (slot ^= (row>>1)&3) via
// pre-swizzled GLOBAL source (gl_lds dest must stay linear) + swizzled ds_read.
// Bijective XCD swizzle, m-major mapping (each XCD keeps one A-panel L2-hot).
// Requires: M%256==0, N%128==0, K%32==0, K>=64.
// EPI: 1 = bias + exact GELU, split-f16 out.  3 = no bias, fp32 out.
template<int EPI>
__global__ __launch_bounds__(512, 2) void k_hgemm(
    const f16* __restrict__ Ah, const f16* __restrict__ Al,
    const f16* __restrict__ Bh, const f16* __restrict__ Bl,
    const float* __restrict__ bias,
    float* __restrict__ outf, f16* __restrict__ outh, f16* __restrict__ outl,
    int M, int N, int K)
{
  // per stage (24576 f16): Ah[256][32] @0 | Al @8192 | Bh[128][32] @16384 | Bl @20480
  __shared__ __align__(16) f16 sm[3 * 24576];
  const int t = threadIdx.x;
  const int w = t >> 6, l15 = t & 15, quad = (t & 63) >> 4;
  const int wm = (w >> 1) * 64, wn = (w & 1) * 64;

  // bijective XCD-aware swizzle (round-robin dispatch -> contiguous chunk per XCD)
  const int nwg = gridDim.x;
  const int orig = blockIdx.x;
  const int q = nwg >> 3, r = nwg & 7;
  const int xcd = orig & 7, oj = orig >> 3;
  const int wgid = (xcd < r ? xcd * (q + 1) : r * (q + 1) + (xcd - r) * q) + oj;
  const int ntn = N >> 7;
  const int m0 = (wgid / ntn) * 256;
  const int n0 = (wgid % ntn) * 128;

  // read-side swizzled k-slot: slot' = quad ^ ((row>>1)&3); row%16 == l15 everywhere
  const int swz8 = (quad ^ ((l15 >> 1) & 3)) * 8;
  // staging: LDS linear (row = s>>2, slot' = s&3); fetch global slot = slot' ^ ((row>>1)&3)
  const int srow = t >> 2;
  const int scol = ((t & 3) ^ ((t >> 3) & 3)) * 8;

  auto stA = [&](const f16* __restrict__ src, int dbase, int k0) {   // 2 loads, rows 0..255
    gl_lds16(src + (size_t)(m0 + srow) * K + k0 + scol, sm + dbase + t * 8);
    gl_lds16(src + (size_t)(m0 + 128 + srow) * K + k0 + scol, sm + dbase + 4096 + t * 8);
  };
  auto stB = [&](const f16* __restrict__ src, int dbase, int k0) {   // 1 load, rows 0..127
    gl_lds16(src + (size_t)(n0 + srow) * K + k0 + scol, sm + dbase + t * 8);
  };

  f32x4 acc[4][4];
#pragma unroll
  for (int i = 0; i < 4; i++)
#pragma unroll
    for (int j = 0; j < 4; j++) acc[i][j] = (f32x4){0.f, 0.f, 0.f, 0.f};

  // prologue: tile 0 -> stage 0, tile 1 -> stage 1 (6 loads each, tile-ordered)
  stA(Ah, 0, 0); stB(Bh, 16384, 0); stA(Al, 8192, 0); stB(Bl, 20480, 0);
  stA(Ah, 24576, 32); stB(Bh, 24576 + 16384, 32);
  stA(Al, 24576 + 8192, 32); stB(Bl, 24576 + 20480, 32);

  const int NT = K >> 5;
  int sb = 0, wsb = 2 * 24576;       // read stage = tt%3, write stage = (tt+2)%3
  for (int tt = 0; tt < NT; ++tt) {
    const int k2 = (tt + 2) << 5;
    // ---- phase A: stage hi(tile tt+2) | counted wait for tile tt | compute j=0,1
    if (tt + 2 < NT) { stA(Ah, wsb, k2); stB(Bh, wsb + 16384, k2); }
    // outstanding: 6(tt) + 6(tt+1) + 3(tt+2 hi) = 15 -> keep 9; tails: 12->6, 6->0.
    if (tt + 2 < NT)      asm volatile("s_waitcnt vmcnt(9)" ::: "memory");
    else if (tt + 1 < NT) asm volatile("s_waitcnt vmcnt(6)" ::: "memory");
    else                  asm volatile("s_waitcnt vmcnt(0)" ::: "memory");
    asm volatile("s_barrier" ::: "memory");
    __builtin_amdgcn_sched_barrier(0);

    f16x8 fah[4], fal[4];
#pragma unroll
    for (int i = 0; i < 4; i++) {
      const int ra = sb + (wm + i * 16 + l15) * 32 + swz8;
      fah[i] = *(const f16x8*)(sm + ra);
      fal[i] = *(const f16x8*)(sm + 8192 + ra);
    }
    const int rb0 = sb + 16384 + (wn + l15) * 32 + swz8;
    const int rb1 = rb0 + 16 * 32;
    f16x8 fbh0 = *(const f16x8*)(sm + rb0), fbl0 = *(const f16x8*)(sm + 4096 + rb0);
    f16x8 fbh1 = *(const f16x8*)(sm + rb1), fbl1 = *(const f16x8*)(sm + 4096 + rb1);
    __builtin_amdgcn_s_setprio(1);
#pragma unroll
    for (int i = 0; i < 4; i++) {
      acc[i][0] = mfma16(fal[i], fbh0, acc[i][0]);
      acc[i][0] = mfma16(fah[i], fbl0, acc[i][0]);
      acc[i][0] = mfma16(fah[i], fbh0, acc[i][0]);
      acc[i][1] = mfma16(fal[i], fbh1, acc[i][1]);
      acc[i][1] = mfma16(fah[i], fbl1, acc[i][1]);
      acc[i][1] = mfma16(fah[i], fbh1, acc[i][1]);
    }
    __builtin_amdgcn_s_setprio(0);
    __builtin_amdgcn_s_barrier();

    // ---- phase B: stage lo(tile tt+2) | compute j=2,3
    if (tt + 2 < NT) { stA(Al, wsb + 8192, k2); stB(Bl, wsb + 20480, k2); }
    const int rb2 = rb0 + 32 * 32;
    const int rb3 = rb0 + 48 * 32;
    f16x8 fbh2 = *(const f16x8*)(sm + rb2), fbl2 = *(const f16x8*)(sm + 4096 + rb2);
    f16x8 fbh3 = *(const f16x8*)(sm + rb3), fbl3 = *(const f16x8*)(sm + 4096 + rb3);
    __builtin_amdgcn_s_setprio(1);
#pragma unroll
    for (int i = 0; i < 4; i++) {
      acc[i][2] = mfma16(fal[i], fbh2, acc[i][2]);
      acc[i][2] = mfma16(fah[i], fbl2, acc[i][2]);
      acc[i][2] = mfma16(fah[i], fbh2, acc[i][2]);
      acc[i][3] = mfma16(fal[i], fbh3, acc[i][3]);
      acc[i][3] = mfma16(fah[i], fbl3, acc[i][3]);
      acc[i][3] = mfma16(fah[i], fbh3, acc[i][3]);
    }
    __builtin_amdgcn_s_setprio(0);
    // all my LDS reads of stage sb must land before any wave starts overwriting it
    // (next iteration's phase A writes stage (tt+3)%3 == tt%3 == sb)
    asm volatile("s_waitcnt lgkmcnt(0)" ::: "memory");
    asm volatile("s_barrier" ::: "memory");
    sb = (sb == 2 * 24576) ? 0 : sb + 24576;
    wsb = (wsb == 2 * 24576) ? 0 : wsb + 24576;
  }

#pragma unroll
  for (int j = 0; j < 4; j++) {
    const int col = n0 + wn + j * 16 + l15;
    float bv = 0.f;
    if constexpr (EPI != 3) bv = bias[col];
#pragma unroll
    for (int i = 0; i < 4; i++) {
      const int rowb = m0 + wm + i * 16 + quad * 4;
#pragma unroll
      for (int r4 = 0; r4 < 4; r4++) {
        const size_t o = (size_t)(rowb + r4) * N + col;
        float v = acc[i][j][r4] + bv;
        if constexpr (EPI == 1) v = 0.5f * v * (1.f + erff(v * 0.70710678118f));
        if constexpr (EPI == 0 || EPI == 1) {
          f16 hv = (f16)v;
          outh[o] = hv;
          outl[o] = (f16)(v - (float)hv);
        } else {
          outf[o] = v;
        }
      }
    }
  }
}

// ---------------- flash attention (split-precision MFMA) ----------------
// qkv hi/lo: [B*T][2304] f16 (q|k|v). Output y hi/lo [B*T][768] f16 split.
__global__ __launch_bounds__(256, 2) void k_attn(
    const f16* __restrict__ qh, const f16* __restrict__ ql,
    const int* __restrict__ idx, f16* __restrict__ yh, f16* __restrict__ yl)
{
  const int qt = blockIdx.x;      // 16 q-tiles of 64
  const int hd = blockIdx.y;      // head
  const int b = blockIdx.z;       // batch
  const int t = threadIdx.x, w = t >> 6, l = t & 63, l15 = l & 15, quad = l >> 4;

  __shared__ float maskadd[T_];
  __shared__ f16 Vth[64][40], Vtl[64][40];
  __shared__ f16 Pldsh[4][16][32], Pldsl[4][16][32];

  for (int i = t; i < T_; i += 256)
    maskadd[i] = (idx[b * T_ + i] == V_ - 1) ? -1e30f : 0.f;

  const size_t rq = (size_t)(b * T_ + qt * 64 + w * 16 + l15) * CQ_ + hd * 64 + quad * 8;
  f16x8 qAh = *(const f16x8*)(qh + rq);
  f16x8 qAl = *(const f16x8*)(ql + rq);
  f16x8 qBh = *(const f16x8*)(qh + rq + 32);
  f16x8 qBl = *(const f16x8*)(ql + rq + 32);

  f32x4 O[4];
  float m[4], lsum[4];
#pragma unroll
  for (int i = 0; i < 4; i++) { O[i] = (f32x4){0.f, 0.f, 0.f, 0.f}; m[i] = -1e30f; lsum[i] = 0.f; }

  for (int kc = 0; kc < T_; kc += 32) {
    __syncthreads();
    {   // stage V chunk transposed: Vt[d][key]
      int key = t >> 3, dg = (t & 7) * 8;
      size_t rv = (size_t)(b * T_ + kc + key) * CQ_ + 1536 + hd * 64 + dg;
      f16x8 vh = *(const f16x8*)(qh + rv);
      f16x8 vl = *(const f16x8*)(ql + rv);
#pragma unroll
      for (int j = 0; j < 8; j++) { Vth[dg + j][key] = vh[j]; Vtl[dg + j][key] = vl[j]; }
    }
    const size_t rk = (size_t)(b * T_ + kc + l15) * CQ_ + 768 + hd * 64 + quad * 8;
    f16x8 k0Ah = *(const f16x8*)(qh + rk);
    f16x8 k0Al = *(const f16x8*)(ql + rk);
    f16x8 k0Bh = *(const f16x8*)(qh + rk + 32);
    f16x8 k0Bl = *(const f16x8*)(ql + rk + 32);
    f16x8 k1Ah = *(const f16x8*)(qh + rk + 16 * CQ_);
    f16x8 k1Al = *(const f16x8*)(ql + rk + 16 * CQ_);
    f16x8 k1Bh = *(const f16x8*)(qh + rk + 16 * CQ_ + 32);
    f16x8 k1Bl = *(const f16x8*)(ql + rk + 16 * CQ_ + 32);

    f32x4 S0 = {0.f, 0.f, 0.f, 0.f}, S1 = {0.f, 0.f, 0.f, 0.f};
    S0 = mfma16(qAl, k0Ah, S0); S0 = mfma16(qAh, k0Al, S0); S0 = mfma16(qAh, k0Ah, S0);
    S0 = mfma16(qBl, k0Bh, S0); S0 = mfma16(qBh, k0Bl, S0); S0 = mfma16(qBh, k0Bh, S0);
    S1 = mfma16(qAl, k1Ah, S1); S1 = mfma16(qAh, k1Al, S1); S1 = mfma16(qAh, k1Ah, S1);
    S1 = mfma16(qBl, k1Bh, S1); S1 = mfma16(qBh, k1Bl, S1); S1 = mfma16(qBh, k1Bh, S1);

    const float mk0 = maskadd[kc + l15];
    const float mk1 = maskadd[kc + 16 + l15];
    float alpha[4];
#pragma unroll
    for (int r = 0; r < 4; r++) {
      float s0 = S0[r] * 0.125f + mk0;
      float s1 = S1[r] * 0.125f + mk1;
      float mx = fmaxf(s0, s1);
#pragma unroll
      for (int d = 1; d < 16; d <<= 1) mx = fmaxf(mx, __shfl_xor(mx, d));
      float mn = fmaxf(m[r], mx);
      float al = __expf(m[r] - mn);
      float p0 = __expf(s0 - mn);
      float p1 = __expf(s1 - mn);
      float rs = p0 + p1;
#pragma unroll
      for (int d = 1; d < 16; d <<= 1) rs += __shfl_xor(rs, d);
      lsum[r] = lsum[r] * al + rs;
      m[r] = mn;
      alpha[r] = al;
      f16 h0 = (f16)p0;
      Pldsh[w][quad * 4 + r][l15] = h0;
      Pldsl[w][quad * 4 + r][l15] = (f16)(p0 - (float)h0);
      f16 h1 = (f16)p1;
      Pldsh[w][quad * 4 + r][16 + l15] = h1;
      Pldsl[w][quad * 4 + r][16 + l15] = (f16)(p1 - (float)h1);
    }
#pragma unroll
    for (int dc = 0; dc < 4; dc++)
#pragma unroll
      for (int r = 0; r < 4; r++) O[dc][r] *= alpha[r];
    __syncthreads();
    f16x8 pfh = *(const f16x8*)(&Pldsh[w][l15][quad * 8]);
    f16x8 pfl = *(const f16x8*)(&Pldsl[w][l15][quad * 8]);
#pragma unroll
    for (int dc = 0; dc < 4; dc++) {
      f16x8 vfh = *(const f16x8*)(&Vth[dc * 16 + l15][quad * 8]);
      f16x8 vfl = *(const f16x8*)(&Vtl[dc * 16 + l15][quad * 8]);
      O[dc] = mfma16(pfl, vfh, O[dc]);
      O[dc] = mfma16(pfh, vfl, O[dc]);
      O[dc] = mfma16(pfh, vfh, O[dc]);
    }
  }

  float inv[4];
#pragma unroll
  for (int r = 0; r < 4; r++) inv[r] = 1.f / lsum[r];
  const int qr = qt * 64 + w * 16 + quad * 4;
#pragma unroll
  for (int r = 0; r < 4; r++) {
    size_t yo = (size_t)(b * T_ + qr + r) * C_ + hd * 64 + l15;
#pragma unroll
    for (int dc = 0; dc < 4; dc++) {
      float v = O[dc][r] * inv[r];
      f16 hv = (f16)v;
      yh[yo + dc * 16] = hv;
      yl[yo + dc * 16] = (f16)(v - (float)hv);
    }
  }
}

// ---------------- per-row max/argmax/logsumexp (single pass) ----------------
__global__ __launch_bounds__(256) void k_rowstat(const float* __restrict__ logits,
    float* __restrict__ logZ, float* __restrict__ out)
{
  __shared__ float smax[256], ssum[256];
  __shared__ int sidx[256];
  const int row = blockIdx.x, t = threadIdx.x;
  const float* lr = logits + (size_t)row * V_;
  float bm = -3e38f, bs = 0.f;
  int bi = 0;
  for (int c = t; c < V_; c += 256) {
    float v = lr[c];
    if (v > bm) { bs = bs * __expf(bm - v) + 1.f; bm = v; bi = c; }
    else bs += __expf(v - bm);
  }
  smax[t] = bm; ssum[t] = bs; sidx[t] = bi;
  __syncthreads();
  for (int off = 128; off > 0; off >>= 1) {
    if (t < off) {
      float m1 = smax[t], m2 = smax[t + off];
      float s1 = ssum[t], s2 = ssum[t + off];
      int i1 = sidx[t], i2 = sidx[t + off];
      float M = fmaxf(m1, m2);
      ssum[t] = s1 * __expf(m1 - M) + s2 * __expf(m2 - M);
      smax[t] = M;
      sidx[t] = (m2 > m1 || (m2 == m1 && i2 < i1)) ? i2 : i1;   // np.argmax: first max
    }
    __syncthreads();
  }
  if (t == 0) {
    float sum = ssum[0];
    logZ[row] = smax[0] + logf(sum);
    out[row] = (float)sidx[0];            // seq_new
    out[B_ * T_ + row] = 1.f / sum;       // seq_new_q = exp(max - logZ)
  }
}

// ---------------- logsoftmax write ----------------
__global__ __launch_bounds__(256) void k_lsm(const float* __restrict__ logits,
    const float* __restrict__ logZ, float* __restrict__ out2)
{
  const int row = blockIdx.y;
  const int c4 = blockIdx.x * 256 + threadIdx.x;
  if (c4 >= V_ / 4) return;
  const float lz = logZ[row];
  float4 v = *(const float4*)(logits + (size_t)row * V_ + c4 * 4);
  float4 o = {v.x - lz, v.y - lz, v.z - lz, v.w - lz};
  *(float4*)(out2 + (size_t)row * V_ + c4 * 4) = o;
}

// ---------------- host ----------------
extern "C" void kernel_launch(void* const* d_in, const int* in_sizes, int n_in,
                              void* d_out, int out_size, void* d_ws, size_t ws_size,
                              hipStream_t stream)
{
  (void)in_sizes; (void)n_in; (void)out_size; (void)ws_size;
  const int* idx = (const int*)d_in[0];
  const float* tok = (const float*)d_in[1];
  const float* pos = (const float*)d_in[2];
  const float* Wq = (const float*)d_in[3];
  const float* bq = (const float*)d_in[4];
  const float* Wk = (const float*)d_in[5];
  const float* bk = (const float*)d_in[6];
  const float* Wv = (const float*)d_in[7];
  const float* bv = (const float*)d_in[8];
  const float* Wo = (const float*)d_in[9];
  const float* bo = (const float*)d_in[10];
  const float* ln1g = (const float*)d_in[11];
  const float* ln1b = (const float*)d_in[12];
  const float* ln2g = (const float*)d_in[13];
  const float* ln2b = (const float*)d_in[14];
  const float* W1 = (const float*)d_in[15];
  const float* b1 = (const float*)d_in[16];
  const float* W2 = (const float*)d_in[17];
  const float* b2 = (const float*)d_in[18];
  const float* lnfg = (const float*)d_in[19];
  const float* lnfb = (const float*)d_in[20];
  const float* Wh = (const float*)d_in[21];

  char* ws = (char*)d_ws;
  size_t off = 0;
  auto alloc = [&](size_t bytes) -> char* {
    char* p = ws + off; off += (bytes + 255) & ~(size_t)255; return p;
  };
  // persistent region
  float* x    = (float*)alloc((size_t)4096 * 768 * 4);
  f16* h_hi   = (f16*)alloc((size_t)4096 * 768 * 2);
  f16* h_lo   = (f16*)alloc((size_t)4096 * 768 * 2);
  f16* Wht_hi = (f16*)alloc((size_t)32000 * 768 * 2);
  f16* Wht_lo = (f16*)alloc((size_t)32000 * 768 * 2);
  float* logZ = (float*)alloc((size_t)4096 * 4);
  float* bqkv = (float*)alloc((size_t)6 * 2304 * 4);
  // zone A: logits (written only by head GEMM, after which everything below is dead)
  float* logits = (float*)(ws + off);
  // per-layer weights + activations, aliased under logits' 524 MB footprint window
  f16* Wqkv_hi = (f16*)alloc((size_t)6 * 2304 * 768 * 2);
  f16* Wqkv_lo = (f16*)alloc((size_t)6 * 2304 * 768 * 2);
  f16* Wo_hi   = (f16*)alloc((size_t)6 * 768 * 768 * 2);
  f16* Wo_lo   = (f16*)alloc((size_t)6 * 768 * 768 * 2);
  f16* W1_hi   = (f16*)alloc((size_t)6 * 3072 * 768 * 2);
  f16* W1_lo   = (f16*)alloc((size_t)6 * 3072 * 768 * 2);
  f16* W2_hi   = (f16*)alloc((size_t)6 * 768 * 3072 * 2);
  f16* W2_lo   = (f16*)alloc((size_t)6 * 768 * 3072 * 2);
  f16* qkv_hi  = (f16*)alloc((size_t)4096 * 2304 * 2);
  f16* qkv_lo  = (f16*)alloc((size_t)4096 * 2304 * 2);
  f16* y_hi    = (f16*)alloc((size_t)4096 * 768 * 2);
  f16* y_lo    = (f16*)alloc((size_t)4096 * 768 * 2);
  f16* hid_hi  = (f16*)alloc((size_t)4096 * 3072 * 2);
  f16* hid_lo  = (f16*)alloc((size_t)4096 * 3072 * 2);

  float* out = (float*)d_out;
  float* out2 = out + 8192;

  // weight prep: transpose + split
  k_tsplit<<<dim3(12, 12, 6), 256, 0, stream>>>(Wq, Wqkv_hi, Wqkv_lo, 768, 768, 589824LL, 1769472LL);
  k_tsplit<<<dim3(12, 12, 6), 256, 0, stream>>>(Wk, Wqkv_hi + 589824, Wqkv_lo + 589824, 768, 768, 589824LL, 1769472LL);
  k_tsplit<<<dim3(12, 12, 6), 256, 0, stream>>>(Wv, Wqkv_hi + 1179648, Wqkv_lo + 1179648, 768, 768, 589824LL, 1769472LL);
  k_tsplit<<<dim3(12, 12, 6), 256, 0, stream>>>(Wo, Wo_hi, Wo_lo, 768, 768, 589824LL, 589824LL);
  k_tsplit<<<dim3(48, 12, 6), 256, 0, stream>>>(W1, W1_hi, W1_lo, 768, 3072, 2359296LL, 2359296LL);
  k_tsplit<<<dim3(12, 48, 6), 256, 0, stream>>>(W2, W2_hi, W2_lo, 3072, 768, 2359296LL, 2359296LL);
  k_tsplit<<<dim3(500, 12, 1), 256, 0, stream>>>(Wh, Wht_hi, Wht_lo, 768, 32000, 0LL, 0LL);
  k_bqkv<<<54, 256, 0, stream>>>(bq, bk, bv, bqkv);
  k_embed<<<3072, 256, 0, stream>>>(idx, tok, pos, x);

  for (int lyr = 0; lyr < 6; lyr++) {
    k_ln<<<4096, 256, 0, stream>>>(x, ln1g + lyr * 768, ln1b + lyr * 768, h_hi, h_lo);
    k_gemm<0><<<dim3(18, 32), 256, 0, stream>>>(h_hi, h_lo,
        Wqkv_hi + (size_t)lyr * 1769472, Wqkv_lo + (size_t)lyr * 1769472,
        bqkv + lyr * 2304, nullptr, nullptr, qkv_hi, qkv_lo, 4096, 2304, 768);
    k_attn<<<dim3(16, 12, 4), 256, 0, stream>>>(qkv_hi, qkv_lo, idx, y_hi, y_lo);
    k_gemm<2><<<dim3(6, 32), 256, 0, stream>>>(y_hi, y_lo,
        Wo_hi + (size_t)lyr * 589824, Wo_lo + (size_t)lyr * 589824,
        bo + lyr * 768, x, x, nullptr, nullptr, 4096, 768, 768);
    k_ln<<<4096, 256, 0, stream>>>(x, ln2g + lyr * 768, ln2b + lyr * 768, h_hi, h_lo);
    k_hgemm<1><<<dim3(384), 512, 0, stream>>>(h_hi, h_lo,
        W1_hi + (size_t)lyr * 2359296, W1_lo + (size_t)lyr * 2359296,
        b1 + lyr * 3072, nullptr, hid_hi, hid_lo, 4096, 3072, 768);
    k_gemm<2><<<dim3(6, 32), 256, 0, stream>>>(hid_hi, hid_lo,
        W2_hi + (size_t)lyr * 2359296, W2_lo + (size_t)lyr * 2359296,
        b2 + lyr * 768, x, x, nullptr, nullptr, 4096, 768, 3072);
  }
  k_ln<<<4096, 256, 0, stream>>>(x, lnfg, lnfb, h_hi, h_lo);
  k_hgemm<3><<<dim3(4000), 512, 0, stream>>>(h_hi, h_lo, Wht_hi, Wht_lo,
      nullptr, logits, nullptr, nullptr, 4096, 32000, 768);
  k_rowstat<<<4096, 256, 0, stream>>>(logits, logZ, out);
  k_lsm<<<dim3(32, 4096), 256, 0, stream>>>(logits, logZ, out2);
}